// Round 8
// baseline (213.061 us; speedup 1.0000x reference)
//
#include <hip/hip_runtime.h>
#include <cstdint>
#include <cstddef>

#define B_   256
#define D_   2048
#define U_   2048
#define NTOT 8192    // 4*U
#define BM   128
#define BN   64
#define BK   32
#define KSP  4
#define KC   1024    // K per ksplit (ksplit=4 over K=4096)
#define ITERS (KC / BK)   // 32

typedef _Float16 half8 __attribute__((ext_vector_type(8)));
typedef float floatx16 __attribute__((ext_vector_type(16)));

// ---------------------------------------------------------------------------
// prep: [x|h] fp32 -> f16, chunk-major layout [chunk=k/8][row][8] so the GEMM
// stages A with contiguous global_load_lds and reads fragments as ds_read_b128.
// ---------------------------------------------------------------------------
__global__ __launch_bounds__(256) void prep_kernel(
    const float* __restrict__ x, const float* __restrict__ h,
    _Float16* __restrict__ Ahi)
{
    int gid   = blockIdx.x * 256 + threadIdx.x;   // 131072 total
    int chunk = gid >> 8;                         // 0..511
    int row   = gid & 255;                        // 0..255
    int col0  = chunk * 8;
    const float* src = (col0 < D_) ? (x + row * D_ + col0)
                                   : (h + row * U_ + (col0 - D_));
    float4 v0 = *(const float4*)(src);
    float4 v1 = *(const float4*)(src + 4);
    float v[8] = {v0.x, v0.y, v0.z, v0.w, v1.x, v1.y, v1.z, v1.w};
    half8 hi;
#pragma unroll
    for (int i = 0; i < 8; ++i) hi[i] = (_Float16)v[i];
    *(half8*)(Ahi + (chunk * 256 + row) * 8) = hi;
}

// ---------------------------------------------------------------------------
// GEMM v9: occupancy lever (m132->m97: 2->3 blocks/CU = +72%).
// Tile 128x64, BK=32, 256 thr = 4 waves of 64x32 (2 x 32x32x16 accs).
// Grid (256 mn-tiles, ksp=4) = 1024 blocks = 4 blocks/CU RESIDENT
// (LDS 24 KB, VGPR <=128 via launch_bounds(256,4)) -> 16 waves/CU,
// double every previous round.  Same verified v8 skeleton: counted vmcnt
// (floor 8, never 0 in loop), B reg-staged fp32->f16 with 2-step lead,
// A via global_load_lds with 1-step lead, all LDS accesses lane-contiguous
// 16B (zero bank conflicts), raw s_barrier, f16 P partials.
// ---------------------------------------------------------------------------
__global__ __launch_bounds__(256, 4) void gemm_kernel(
    const _Float16* __restrict__ Ahi,
    const float* __restrict__ Wz, const float* __restrict__ Wi,
    const float* __restrict__ Wf, const float* __restrict__ Wo,
    const float* __restrict__ Uz, const float* __restrict__ Ui,
    const float* __restrict__ Uf, const float* __restrict__ Uo,
    _Float16* __restrict__ P)
{
    __shared__ __align__(16) _Float16 sA[2][4 * 128 * 8];   // 2 x 8 KB
    __shared__ __align__(16) _Float16 sB[2][4 * 64 * 8];    // 2 x 4 KB

    const int t    = threadIdx.x;
    const int w    = t >> 6;          // wave 0..3
    const int lane = t & 63;
    const int lg   = lane >> 5;
    const int lm   = lane & 31;
    const int wm   = w >> 1;          // 0/1: M half (64 rows)
    const int wn   = w & 1;           // 0/1: N half (32 cols)

    // block mapping: 256 mn-tiles; m-twins (same nt) pinned to one XCD.
    const int bx = blockIdx.x;        // 0..255
    const int mt = (bx >> 3) & 1;
    const int nt = ((bx >> 4) << 3) | (bx & 7);   // 0..127
    const int ks = blockIdx.y;        // 0..3

    const int m0 = mt * BM;
    const int n0 = nt * BN;           // within 8192
    const int g  = n0 >> 11;          // gate 0..3
    const int c0 = n0 & (U_ - 1);

    const float* wsel[8] = {Wz, Wi, Wf, Wo, Uz, Ui, Uf, Uo};
    const float* Bm = wsel[(ks >> 1) * 4 + g];   // ks 0,1 -> W*; 2,3 -> U*
    const int km = (ks & 1) * 1024;              // row base within matrix
    const int chunkbase = ks * 128;              // A chunk base (chunk = k/8)

    // --- A staging (2 x gload_lds/thread): instr i: chunk c = 2i + (t>>7),
    //     row = t&127; wave-uniform LDS base + lane*16B.
    const int arow  = t & 127;
    const int ahalf = t >> 7;

    // --- B staging: thread owns col bcol = t&63, k-slot sb = t>>6 (=w),
    //     8 coalesced fp32 loads -> cvt -> one ds_write_b128.
    const int bcol = t & 63;
    const int sb   = t >> 6;
    const float* Bg = Bm + (size_t)km * U_ + c0 + bcol;

    floatx16 acc0 = {}, acc1 = {};
    float rbA[8], rbB[8];

#define ISSUE_A(tt, buf)                                                      \
    {                                                                         \
        _Pragma("unroll")                                                     \
        for (int i = 0; i < 2; ++i) {                                         \
            int c = 2 * i + ahalf;                                            \
            __builtin_amdgcn_global_load_lds(                                 \
                (const __attribute__((address_space(1))) void*)(              \
                    Ahi + (size_t)(chunkbase + (tt) * 4 + c) * 2048           \
                        + (m0 + arow) * 8),                                   \
                (__attribute__((address_space(3))) void*)(                    \
                    &sA[buf][c * 1024 + arow * 8]),                           \
                16, 0, 0);                                                    \
        }                                                                     \
    }

#define ISSUE_B(tt, rb)                                                       \
    {                                                                         \
        _Pragma("unroll")                                                     \
        for (int j = 0; j < 8; ++j)                                           \
            rb[j] = Bg[(size_t)((tt) * 32 + sb * 8 + j) * U_];                \
    }

#define WRITE_B(rb, buf)                                                      \
    {                                                                         \
        half8 hv;                                                             \
        _Pragma("unroll")                                                     \
        for (int j = 0; j < 8; ++j) hv[j] = (_Float16)rb[j];                  \
        *(half8*)(&sB[buf][sb * 512 + bcol * 8]) = hv;                        \
    }

#define COMPUTE(cur)                                                          \
    {                                                                         \
        __builtin_amdgcn_s_setprio(1);                                        \
        _Pragma("unroll")                                                     \
        for (int kin = 0; kin < 2; ++kin) {                                   \
            int cs = kin * 2 + lg;                                            \
            half8 a0 = *(const half8*)(&sA[cur][cs * 1024 + (wm * 64 + lm) * 8]);      \
            half8 a1 = *(const half8*)(&sA[cur][cs * 1024 + (wm * 64 + 32 + lm) * 8]); \
            half8 b0 = *(const half8*)(&sB[cur][cs * 512 + (wn * 32 + lm) * 8]);       \
            acc0 = __builtin_amdgcn_mfma_f32_32x32x16_f16(a0, b0, acc0, 0, 0, 0);      \
            acc1 = __builtin_amdgcn_mfma_f32_32x32x16_f16(a1, b0, acc1, 0, 0, 0);      \
        }                                                                     \
        __builtin_amdgcn_s_setprio(0);                                        \
    }

    // ---- prologue: B(0)[8] -> A(0)[2] -> B(1)[8]; retire B(0) at vmcnt(10);
    //      write B(0); retire A(0) at vmcnt(8); barrier.  Leaves B(1)=8.
    ISSUE_B(0, rbA);
    ISSUE_A(0, 0);
    ISSUE_B(1, rbB);
    asm volatile("s_waitcnt vmcnt(10)" ::: "memory");
    WRITE_B(rbA, 0);
    asm volatile("s_waitcnt vmcnt(8) lgkmcnt(0)" ::: "memory");
    __builtin_amdgcn_s_barrier();

    // ---- main loop (2x unrolled; top-of-step outstanding = B(t+1)=8)
    for (int tt = 0; tt < ITERS - 2; tt += 2) {
        // even step t=tt: compute buf0; rbB holds B(t+1)
        ISSUE_A(tt + 1, 1);
        ISSUE_B(tt + 2, rbA);
        COMPUTE(0);
        asm volatile("s_waitcnt vmcnt(10)" ::: "memory");   // B(t+1) regs done
        WRITE_B(rbB, 1);
        asm volatile("s_waitcnt vmcnt(8) lgkmcnt(0)" ::: "memory"); // A(t+1)
        __builtin_amdgcn_s_barrier();

        // odd step t=tt+1: compute buf1; rbA holds B(t+1)
        ISSUE_A(tt + 2, 0);
        ISSUE_B(tt + 3, rbB);
        COMPUTE(1);
        asm volatile("s_waitcnt vmcnt(10)" ::: "memory");
        WRITE_B(rbA, 0);
        asm volatile("s_waitcnt vmcnt(8) lgkmcnt(0)" ::: "memory");
        __builtin_amdgcn_s_barrier();
    }

    // ---- epilogue: step ITERS-2 (even, buf0); rbB holds B(ITERS-1)
    ISSUE_A(ITERS - 1, 1);
    COMPUTE(0);
    asm volatile("s_waitcnt vmcnt(2)" ::: "memory");        // B(ITERS-1) done
    WRITE_B(rbB, 1);
    asm volatile("s_waitcnt vmcnt(0) lgkmcnt(0)" ::: "memory");
    __builtin_amdgcn_s_barrier();
    // step ITERS-1 (odd, buf1)
    COMPUTE(1);

#undef ISSUE_A
#undef ISSUE_B
#undef WRITE_B
#undef COMPUTE

    // C/D layout: col=lane&31, row=(r&3)+8*(r>>2)+4*(lane>>5).  P is f16.
    _Float16* Pks = P + (size_t)ks * ((size_t)B_ * NTOT);
    const int colg = n0 + wn * 32 + lm;
#pragma unroll
    for (int r = 0; r < 16; ++r) {
        int m = m0 + wm * 64 + 4 * lg + (r & 3) + 8 * (r >> 2);
        Pks[(size_t)m * NTOT + colg] = (_Float16)acc0[r];
    }
#pragma unroll
    for (int r = 0; r < 16; ++r) {
        int m = m0 + wm * 64 + 32 + 4 * lg + (r & 3) + 8 * (r >> 2);
        Pks[(size_t)m * NTOT + colg] = (_Float16)acc1[r];
    }
}

// ---------------------------------------------------------------------------
// gates: reduce 4 f16 partials, add bias, sLSTM exponential-gate math,
// out = stack([h_t, c_t, n_t, m_t]).  8 outputs per thread.
// ---------------------------------------------------------------------------
__global__ __launch_bounds__(256) void gates_kernel(
    const _Float16* __restrict__ P,
    const float* __restrict__ c_prev, const float* __restrict__ n_prev,
    const float* __restrict__ m_prev,
    const float* __restrict__ bz, const float* __restrict__ bi,
    const float* __restrict__ bf, const float* __restrict__ bo,
    float* __restrict__ out)
{
    const size_t PS = (size_t)B_ * NTOT;
    const int OS = B_ * U_;
    int gid = blockIdx.x * 256 + threadIdx.x;   // 65536
    int m = gid >> 8;
    int u = (gid & 255) * 8;

    float pre[4][8];
#pragma unroll
    for (int gi = 0; gi < 4; ++gi) {
#pragma unroll
        for (int e = 0; e < 8; ++e) pre[gi][e] = 0.0f;
#pragma unroll
        for (int ksp = 0; ksp < KSP; ++ksp) {
            half8 v = *(const half8*)(P + (size_t)ksp * PS
                                        + (size_t)m * NTOT + gi * 2048 + u);
#pragma unroll
            for (int e = 0; e < 8; ++e) pre[gi][e] += (float)v[e];
        }
    }

    float bza[8], bia[8], bfa[8], boa[8], cpa[8], npa[8], mpa[8];
    *(float4*)(bza)     = *(const float4*)(bz + u);
    *(float4*)(bza + 4) = *(const float4*)(bz + u + 4);
    *(float4*)(bia)     = *(const float4*)(bi + u);
    *(float4*)(bia + 4) = *(const float4*)(bi + u + 4);
    *(float4*)(bfa)     = *(const float4*)(bf + u);
    *(float4*)(bfa + 4) = *(const float4*)(bf + u + 4);
    *(float4*)(boa)     = *(const float4*)(bo + u);
    *(float4*)(boa + 4) = *(const float4*)(bo + u + 4);
    *(float4*)(cpa)     = *(const float4*)(c_prev + m * U_ + u);
    *(float4*)(cpa + 4) = *(const float4*)(c_prev + m * U_ + u + 4);
    *(float4*)(npa)     = *(const float4*)(n_prev + m * U_ + u);
    *(float4*)(npa + 4) = *(const float4*)(n_prev + m * U_ + u + 4);
    *(float4*)(mpa)     = *(const float4*)(m_prev + m * U_ + u);
    *(float4*)(mpa + 4) = *(const float4*)(m_prev + m * U_ + u + 4);

    float hr[8], cr[8], nr[8], mr[8];
#pragma unroll
    for (int e = 0; e < 8; ++e) {
        float zt = pre[0][e] + bza[e];
        float it = pre[1][e] + bia[e];
        float ft = pre[2][e] + bfa[e];
        float ot = pre[3][e] + boa[e];
        float mp = mpa[e];
        float m_t = fmaxf(it + mp, it);
        float i_t = expf(it - m_t);
        float f_t = expf(ft + mp - m_t);
        float o_t = 1.0f / (1.0f + expf(-ot));
        float z_t = tanhf(zt);
        float c_t = f_t * cpa[e] + i_t * z_t;
        float n_t = f_t * npa[e] + i_t;
        float h_t = o_t * (c_t / (n_t + 1e-8f));
        hr[e] = h_t; cr[e] = c_t; nr[e] = n_t; mr[e] = m_t;
    }
    float* ob = out + m * U_ + u;
    *(float4*)(ob + 0 * OS)     = *(float4*)(hr);
    *(float4*)(ob + 0 * OS + 4) = *(float4*)(hr + 4);
    *(float4*)(ob + 1 * OS)     = *(float4*)(cr);
    *(float4*)(ob + 1 * OS + 4) = *(float4*)(cr + 4);
    *(float4*)(ob + 2 * OS)     = *(float4*)(nr);
    *(float4*)(ob + 2 * OS + 4) = *(float4*)(nr + 4);
    *(float4*)(ob + 3 * OS)     = *(float4*)(mr);
    *(float4*)(ob + 3 * OS + 4) = *(float4*)(mr + 4);
}

extern "C" void kernel_launch(void* const* d_in, const int* in_sizes, int n_in,
                              void* d_out, int out_size, void* d_ws, size_t ws_size,
                              hipStream_t stream)
{
    const float* x  = (const float*)d_in[0];
    const float* h  = (const float*)d_in[1];
    const float* cp = (const float*)d_in[2];
    const float* np = (const float*)d_in[3];
    const float* mp = (const float*)d_in[4];
    const float* Wz = (const float*)d_in[5];
    const float* Wi = (const float*)d_in[6];
    const float* Wf = (const float*)d_in[7];
    const float* Wo = (const float*)d_in[8];
    const float* bz = (const float*)d_in[9];
    const float* bi = (const float*)d_in[10];
    const float* bf = (const float*)d_in[11];
    const float* bo = (const float*)d_in[12];
    const float* Uz = (const float*)d_in[13];
    const float* Ui = (const float*)d_in[14];
    const float* Uf = (const float*)d_in[15];
    const float* Uo = (const float*)d_in[16];

    // workspace: P (f16, 4 partials) = 4*256*8192*2 = 16.8 MB, then Ahi 2 MB
    _Float16* P   = (_Float16*)d_ws;
    _Float16* Ahi = (_Float16*)((char*)d_ws
                     + (size_t)KSP * B_ * NTOT * sizeof(_Float16));

    prep_kernel<<<512, 256, 0, stream>>>(x, h, Ahi);
    gemm_kernel<<<dim3(256, KSP), 256, 0, stream>>>(Ahi,
        Wz, Wi, Wf, Wo, Uz, Ui, Uf, Uo, P);
    gates_kernel<<<256, 256, 0, stream>>>(P, cp, np, mp, bz, bi, bf, bo,
        (float*)d_out);
}